// Round 1
// baseline (749.957 us; speedup 1.0000x reference)
//
#include <hip/hip_runtime.h>
#include <stdint.h>

#define B_    16
#define AT_   96
#define NBR_  12
#define FN_   64
#define FE_   64
#define M1    (B_*AT_*NBR_)   /* 18432 */
#define R_    (B_*AT_)        /* 1536  */
#define K1Q   128             /* layer-1 input features */
#define N1    512             /* H1 */
#define K2Q   512
#define N2    128

/* ---- workspace layout (bytes) ---- */
#define OFF_SCAL  0u
#define OFF_Q1T   256u
#define OFF_W1E   (OFF_Q1T + (size_t)M1*K1Q)          /* 2,359,552 */
#define OFF_B1    (OFF_W1E + (size_t)K1Q*8*N1*4)      /* +2 MB */
#define OFF_H     (OFF_B1 + (size_t)N1*4)
#define OFF_Q2T   (OFF_H + (size_t)M1*N1*4)           /* +37.75 MB */
#define OFF_W2E   (OFF_Q2T + (size_t)M1*K2Q)          /* +9.44 MB */
#define OFF_B2    (OFF_W2E + (size_t)K2Q*8*N2*4)      /* +2 MB */
#define OFF_C2    OFF_H                                /* alias: h dead after quant */
#define OFF_NS    (OFF_H + (size_t)M1*N2*4)            /* inside old h region */

__device__ __forceinline__ unsigned int enc_f(float f) {
    unsigned int u = __float_as_uint(f);
    return (u & 0x80000000u) ? ~u : (u | 0x80000000u);
}
__device__ __forceinline__ float dec_f(unsigned int u) {
    return __uint_as_float((u & 0x80000000u) ? (u & 0x7FFFFFFFu) : ~u);
}

__global__ void k_init(unsigned int* scal) {
    if (threadIdx.x == 0) {
        scal[0] = 0xFFFFFFFFu; scal[1] = 0u;   /* mn1 / mx1 (encoded) */
        scal[2] = 0xFFFFFFFFu; scal[3] = 0u;   /* mn2 / mx2 */
    }
}

/* global min/max over c1 = node ∪ edge (broadcast doesn't change min/max) */
__global__ __launch_bounds__(256) void k_minmax_c1(const float* __restrict__ node,
                                                   const float* __restrict__ edge,
                                                   unsigned int* __restrict__ scal) {
    const int nn = B_*AT_*FN_;
    const int ntot = nn + M1*FE_;
    float mn = 3.0e38f, mx = -3.0e38f;
    for (int idx = blockIdx.x*blockDim.x + threadIdx.x; idx < ntot; idx += gridDim.x*blockDim.x) {
        float x = (idx < nn) ? node[idx] : edge[idx - nn];
        mn = fminf(mn, x); mx = fmaxf(mx, x);
    }
    __shared__ float smn[256], smx[256];
    smn[threadIdx.x] = mn; smx[threadIdx.x] = mx; __syncthreads();
    for (int s = 128; s > 0; s >>= 1) {
        if (threadIdx.x < s) {
            smn[threadIdx.x] = fminf(smn[threadIdx.x], smn[threadIdx.x+s]);
            smx[threadIdx.x] = fmaxf(smx[threadIdx.x], smx[threadIdx.x+s]);
        }
        __syncthreads();
    }
    if (threadIdx.x == 0) { atomicMin(&scal[0], enc_f(smn[0])); atomicMax(&scal[1], enc_f(smx[0])); }
}

/* expanded weights: We[k=i*8+b][o] = 2^b * s * (w[o,i] + 0.1*|w[o,i]|*eps[b,o,i]),
   s = (mx-mn)/255 folded from the epilogue scale */
template<int KQ, int N>
__global__ __launch_bounds__(256) void k_prep_w(const float* __restrict__ w_clean,
                                                const float* __restrict__ eps,
                                                const unsigned int* __restrict__ scal, int sbase,
                                                float* __restrict__ We) {
    int idx = blockIdx.x*blockDim.x + threadIdx.x;
    if (idx >= KQ*8*N) return;
    float mn = dec_f(scal[sbase]), mx = dec_f(scal[sbase+1]);
    float s = (mx - mn) / 255.0f;
    int o = idx % N;
    int k = idx / N;
    int i = k >> 3, b = k & 7;
    float w = w_clean[o*KQ + i];
    float e = eps[b*(N*KQ) + o*KQ + i];
    float v = w + (e * fabsf(w)) * 0.1f;
    We[idx] = v * ((float)(1 << b) * s);
}

__global__ void k_bias1(const float* __restrict__ cond1, const float* __restrict__ eps1,
                        const unsigned int* __restrict__ scal, float* __restrict__ bias1) {
    int o = blockIdx.x*blockDim.x + threadIdx.x;
    if (o >= N1) return;
    float mn = dec_f(scal[0]);
    float ssum = 0.f;
    for (int i = 0; i < K1Q; i++) {
        float w = cond1[o*K1Q + i];
        float e = eps1[7*(N1*K1Q) + o*K1Q + i];   /* w_noisy[-1] = plane b=7 */
        ssum += w + (e * fabsf(w)) * 0.1f;
    }
    bias1[o] = mn * ssum;
}

__global__ void k_bias2(const float* __restrict__ cond2, const unsigned int* __restrict__ scal,
                        float* __restrict__ bias2) {
    int o = blockIdx.x*blockDim.x + threadIdx.x;
    if (o >= N2) return;
    float mn = dec_f(scal[2]);
    const float* w2 = cond2 + N2*K2Q;   /* cond2[1] — clean second matrix */
    float ssum = 0.f;
    for (int i = 0; i < K2Q; i++) ssum += w2[o*K2Q + i];
    bias2[o] = mn * ssum;
}

/* quantize c1 -> q1T [K1Q][M1] (transposed for coalesced GEMM staging), LDS transpose */
__global__ __launch_bounds__(256) void k_quant_c1(const float* __restrict__ node,
                                                  const float* __restrict__ edge,
                                                  const unsigned int* __restrict__ scal,
                                                  unsigned char* __restrict__ q1T) {
    __shared__ unsigned char tq[128][68];   /* pad 68: stride 17 words, conflict-free */
    const float mn = dec_f(scal[0]), mx = dec_f(scal[1]);
    const float rng = mx - mn;
    const int m0 = blockIdx.x * 64;
    const int tid = threadIdx.x;
    #pragma unroll
    for (int t = 0; t < 32; t++) {
        int idx = tid + t*256;
        int i  = idx & 127;
        int ml = idx >> 7;
        int m  = m0 + ml;
        float x = (i < FN_) ? node[(m/NBR_)*FN_ + i] : edge[(size_t)m*FE_ + (i - FN_)];
        float r = (x - mn) / rng * 255.0f;   /* identical fp32 ops to np -> bit-exact q1 */
        tq[i][ml] = (unsigned char)(int)r;
    }
    __syncthreads();
    #pragma unroll
    for (int t = 0; t < 8; t++) {
        int idx = tid + t*256;
        int row = idx >> 4;
        int c4  = (idx & 15) * 4;
        *(unsigned int*)&q1T[(size_t)row*M1 + m0 + c4] = *(const unsigned int*)&tq[row][c4];
    }
}

/* quantize h -> q2T [K2Q][M1] */
__global__ __launch_bounds__(256) void k_quant_h(const float* __restrict__ h,
                                                 const unsigned int* __restrict__ scal,
                                                 unsigned char* __restrict__ q2T) {
    __shared__ unsigned char tq[128][68];
    const float mn = dec_f(scal[2]), mx = dec_f(scal[3]);
    const float rng = mx - mn;
    const int m0 = blockIdx.x * 64;
    const int i0 = blockIdx.y * 128;
    const int tid = threadIdx.x;
    #pragma unroll
    for (int t = 0; t < 32; t++) {
        int idx = tid + t*256;
        int i  = idx & 127;
        int ml = idx >> 7;
        float x = h[(size_t)(m0+ml)*N1 + i0 + i];
        float r = (x - mn) / rng * 255.0f;
        tq[i][ml] = (unsigned char)(int)r;
    }
    __syncthreads();
    #pragma unroll
    for (int t = 0; t < 8; t++) {
        int idx = tid + t*256;
        int row = idx >> 4;
        int c4  = (idx & 15) * 4;
        *(unsigned int*)&q2T[(size_t)(i0+row)*M1 + m0 + c4] = *(const unsigned int*)&tq[row][c4];
    }
}

/* bit-plane GEMM: out[m,o] = sum_k bit(qT[k/8][m], k%8) * We[k][o] + bias[o]
   BM=128, BN=64, BK=64 planes (8 q-bytes); 256 thr, 8x4 micro-tile.
   EPI1: relu + fused global min/max (for h). */
template<int KQ, int N, bool EPI1>
__global__ __launch_bounds__(256) void k_gemm(const unsigned char* __restrict__ qT,
                                              const float* __restrict__ We,
                                              const float* __restrict__ bias,
                                              float* __restrict__ out,
                                              unsigned int* __restrict__ scal) {
    __shared__ float As[64][128];   /* [k-plane][m] */
    __shared__ float Ws[64][64];    /* [k-plane][o] */
    const int tid = threadIdx.x;
    const int m0 = blockIdx.x * 128;
    const int o0 = blockIdx.y * 64;
    const int ty = tid >> 4, tx = tid & 15;
    const int wrow = tid >> 4;
    const int wc4  = (tid & 15) * 4;
    const int aiq  = tid >> 5;          /* 0..7 q-byte row  */
    const int amq  = (tid & 31) * 4;    /* m offset         */
    float acc[8][4] = {};

    for (int kq0 = 0; kq0 < KQ; kq0 += 8) {
        __syncthreads();
        #pragma unroll
        for (int rr = 0; rr < 4; rr++) {
            int row = wrow + rr*16;
            *(float4*)&Ws[row][wc4] = *(const float4*)&We[(size_t)(kq0*8 + row)*N + o0 + wc4];
        }
        {
            uchar4 qb = *(const uchar4*)&qT[(size_t)(kq0 + aiq)*M1 + m0 + amq];
            #pragma unroll
            for (int b = 0; b < 8; b++) {
                float4 f;
                f.x = (float)((qb.x >> b) & 1);
                f.y = (float)((qb.y >> b) & 1);
                f.z = (float)((qb.z >> b) & 1);
                f.w = (float)((qb.w >> b) & 1);
                *(float4*)&As[aiq*8 + b][amq] = f;
            }
        }
        __syncthreads();
        #pragma unroll 4
        for (int kk = 0; kk < 64; kk++) {
            const float4 a0 = *(const float4*)&As[kk][ty*8];
            const float4 a1 = *(const float4*)&As[kk][ty*8 + 4];
            const float4 wv = *(const float4*)&Ws[kk][tx*4];
            const float a[8] = {a0.x,a0.y,a0.z,a0.w,a1.x,a1.y,a1.z,a1.w};
            const float w[4] = {wv.x,wv.y,wv.z,wv.w};
            #pragma unroll
            for (int r = 0; r < 8; r++)
                #pragma unroll
                for (int c = 0; c < 4; c++)
                    acc[r][c] = fmaf(a[r], w[c], acc[r][c]);
        }
    }

    const float4 bv = *(const float4*)&bias[o0 + tx*4];
    float tmn = 3.0e38f, tmx = -3.0e38f;
    #pragma unroll
    for (int r = 0; r < 8; r++) {
        float4 v;
        v.x = acc[r][0] + bv.x; v.y = acc[r][1] + bv.y;
        v.z = acc[r][2] + bv.z; v.w = acc[r][3] + bv.w;
        if (EPI1) {
            v.x = fmaxf(v.x, 0.f); v.y = fmaxf(v.y, 0.f);
            v.z = fmaxf(v.z, 0.f); v.w = fmaxf(v.w, 0.f);
            tmn = fminf(tmn, fminf(fminf(v.x, v.y), fminf(v.z, v.w)));
            tmx = fmaxf(tmx, fmaxf(fmaxf(v.x, v.y), fmaxf(v.z, v.w)));
        }
        *(float4*)&out[(size_t)(m0 + ty*8 + r)*N + o0 + tx*4] = v;
    }
    if (EPI1) {
        __syncthreads();
        float* red = &As[0][0];
        red[tid] = tmn; red[256 + tid] = tmx;
        __syncthreads();
        for (int s = 128; s > 0; s >>= 1) {
            if (tid < s) {
                red[tid]       = fminf(red[tid],       red[tid + s]);
                red[256 + tid] = fmaxf(red[256 + tid], red[256 + tid + s]);
            }
            __syncthreads();
        }
        if (tid == 0) { atomicMin(&scal[2], enc_f(red[0])); atomicMax(&scal[3], enc_f(red[256])); }
    }
}

/* gate/extract -> sigmoid*tanh*mask, sum over 12 neighbors */
__global__ void k_nbr(const float* __restrict__ c2, const float* __restrict__ mask,
                      float* __restrict__ ns) {
    int r = blockIdx.x;     /* 0..1535 */
    int f = threadIdx.x;    /* 0..63   */
    float s = 0.f;
    #pragma unroll
    for (int n = 0; n < NBR_; n++) {
        int m = r*NBR_ + n;
        float g  = c2[(size_t)m*N2 + f];
        float e  = c2[(size_t)m*N2 + 64 + f];
        float mk = mask[m];
        float sig = 1.0f / (1.0f + expf(-g));
        s += sig * tanhf(e) * mk;
    }
    ns[r*64 + f] = s;
}

/* BatchNorm (batch stats over 1536 rows) + residual + relu; one block per feature */
__global__ __launch_bounds__(256) void k_bn(const float* __restrict__ ns,
                                            const float* __restrict__ node,
                                            const float* __restrict__ gamma,
                                            const float* __restrict__ beta,
                                            float* __restrict__ out) {
    int f = blockIdx.x;
    int tid = threadIdx.x;
    float x[6];
    float s = 0.f, ss = 0.f;
    #pragma unroll
    for (int k = 0; k < 6; k++) {
        int r = tid + k*256;
        x[k] = ns[r*64 + f];
        s += x[k]; ss += x[k]*x[k];
    }
    __shared__ float rs[256], rss[256];
    rs[tid] = s; rss[tid] = ss; __syncthreads();
    for (int st = 128; st > 0; st >>= 1) {
        if (tid < st) { rs[tid] += rs[tid+st]; rss[tid] += rss[tid+st]; }
        __syncthreads();
    }
    float mean = rs[0] / 1536.0f;
    float var  = rss[0] / 1536.0f - mean*mean;
    float denom = sqrtf(var + 1e-5f);
    float g = gamma[f], bt = beta[f];
    #pragma unroll
    for (int k = 0; k < 6; k++) {
        int r = tid + k*256;
        float v = node[r*64 + f] + ((x[k] - mean) / denom * g + bt);
        out[r*64 + f] = fmaxf(v, 0.f);
    }
}

extern "C" void kernel_launch(void* const* d_in, const int* in_sizes, int n_in,
                              void* d_out, int out_size, void* d_ws, size_t ws_size,
                              hipStream_t stream) {
    const float* node  = (const float*)d_in[0];
    const float* edge  = (const float*)d_in[1];
    const float* mask  = (const float*)d_in[2];
    const float* cond1 = (const float*)d_in[3];
    const float* cond2 = (const float*)d_in[4];
    const float* eps1  = (const float*)d_in[5];
    const float* eps2  = (const float*)d_in[6];
    const float* gamma = (const float*)d_in[7];
    const float* beta  = (const float*)d_in[8];
    float* out = (float*)d_out;
    char* ws = (char*)d_ws;

    unsigned int*  scal = (unsigned int*)(ws + OFF_SCAL);
    unsigned char* q1T  = (unsigned char*)(ws + OFF_Q1T);
    float* W1e = (float*)(ws + OFF_W1E);
    float* b1  = (float*)(ws + OFF_B1);
    float* h   = (float*)(ws + OFF_H);
    unsigned char* q2T  = (unsigned char*)(ws + OFF_Q2T);
    float* W2e = (float*)(ws + OFF_W2E);
    float* b2  = (float*)(ws + OFF_B2);
    float* c2  = (float*)(ws + OFF_C2);
    float* ns  = (float*)(ws + OFF_NS);

    k_init<<<1, 64, 0, stream>>>(scal);
    k_minmax_c1<<<512, 256, 0, stream>>>(node, edge, scal);
    k_prep_w<K1Q, N1><<<(K1Q*8*N1 + 255)/256, 256, 0, stream>>>(cond1, eps1, scal, 0, W1e);
    k_bias1<<<(N1 + 63)/64, 64, 0, stream>>>(cond1, eps1, scal, b1);
    k_quant_c1<<<288, 256, 0, stream>>>(node, edge, scal, q1T);
    k_gemm<K1Q, N1, true><<<dim3(144, 8), 256, 0, stream>>>(q1T, W1e, b1, h, scal);
    k_prep_w<K2Q, N2><<<(K2Q*8*N2 + 255)/256, 256, 0, stream>>>(cond2, eps2, scal, 2, W2e);
    k_bias2<<<(N2 + 63)/64, 64, 0, stream>>>(cond2, scal, b2);
    k_quant_h<<<dim3(288, 4), 256, 0, stream>>>(h, scal, q2T);
    k_gemm<K2Q, N2, false><<<dim3(144, 2), 256, 0, stream>>>(q2T, W2e, b2, c2, scal);
    k_nbr<<<1536, 64, 0, stream>>>(c2, mask, ns);
    k_bn<<<64, 256, 0, stream>>>(ns, node, gamma, beta, out);
}

// Round 2
// 212.082 us; speedup vs baseline: 3.5362x; 3.5362x over previous
//
#include <hip/hip_runtime.h>
#include <stdint.h>

#define B_    16
#define AT_   96
#define NBR_  12
#define FN_   64
#define FE_   64
#define M1    (B_*AT_*NBR_)   /* 18432 */
#define R_    (B_*AT_)        /* 1536  */
#define K1Q   128             /* layer-1 input features (bytes per row) */
#define N1    512             /* H1 */
#define K2Q   512
#define N2    128
#define SPLIT2 4

typedef _Float16 f16x8 __attribute__((ext_vector_type(8)));
typedef float    f32x4 __attribute__((ext_vector_type(4)));
typedef __attribute__((address_space(1))) const void gconst_void;
typedef __attribute__((address_space(3))) void lds_void;

/* ---- workspace layout (bytes); all offsets 256-aligned ---- */
#define OFF_SCAL  0u
#define OFF_Q1    256u                                  /* M1*K1Q = 2,359,296 */
#define OFF_W1E   (OFF_Q1  + (size_t)M1*K1Q)            /* fp16 512x1024 = 1 MB */
#define OFF_B1    (OFF_W1E + (size_t)N1*K1Q*8*2)
#define OFF_B2    (OFF_B1  + (size_t)N1*4)
#define OFF_W2E   (OFF_B2  + (size_t)N2*4 + 256)        /* fp16 128x4096 = 1 MB */
#define OFF_Q2    (OFF_W2E + (size_t)N2*K2Q*8*2)        /* M1*K2Q = 9,437,184 */
#define OFF_H     (OFF_Q2  + (size_t)M1*K2Q)            /* fp32 M1*512 = 37.75 MB */
#define OFF_ZP    OFF_H                                  /* alias: h dead after quant_h */
#define OFF_NS    (OFF_H   + (size_t)M1*N1*4)           /* fp32 1536*64 */

__device__ __forceinline__ unsigned int enc_f(float f) {
    unsigned int u = __float_as_uint(f);
    return (u & 0x80000000u) ? ~u : (u | 0x80000000u);
}
__device__ __forceinline__ float dec_f(unsigned int u) {
    return __uint_as_float((u & 0x80000000u) ? (u & 0x7FFFFFFFu) : ~u);
}

__global__ void k_init(unsigned int* scal) {
    if (threadIdx.x == 0) {
        scal[0] = 0xFFFFFFFFu; scal[1] = 0u;   /* mn1 / mx1 (encoded) */
        scal[2] = 0xFFFFFFFFu; scal[3] = 0u;   /* mn2 / mx2 */
    }
}

__global__ __launch_bounds__(256) void k_minmax_c1(const float* __restrict__ node,
                                                   const float* __restrict__ edge,
                                                   unsigned int* __restrict__ scal) {
    const int nn = B_*AT_*FN_;
    const int ntot = nn + M1*FE_;
    float mn = 3.0e38f, mx = -3.0e38f;
    for (int idx = blockIdx.x*blockDim.x + threadIdx.x; idx < ntot; idx += gridDim.x*blockDim.x) {
        float x = (idx < nn) ? node[idx] : edge[idx - nn];
        mn = fminf(mn, x); mx = fmaxf(mx, x);
    }
    __shared__ float smn[256], smx[256];
    smn[threadIdx.x] = mn; smx[threadIdx.x] = mx; __syncthreads();
    for (int s = 128; s > 0; s >>= 1) {
        if (threadIdx.x < s) {
            smn[threadIdx.x] = fminf(smn[threadIdx.x], smn[threadIdx.x+s]);
            smx[threadIdx.x] = fmaxf(smx[threadIdx.x], smx[threadIdx.x+s]);
        }
        __syncthreads();
    }
    if (threadIdx.x == 0) { atomicMin(&scal[0], enc_f(smn[0])); atomicMax(&scal[1], enc_f(smx[0])); }
}

/* expanded fp16 weights, o-major: We[o][k=i*8+b] = fp16( (w+0.1|w|eps_b) * 2^b * s ) */
template<int KQ, int N>
__global__ __launch_bounds__(256) void k_prep_w16(const float* __restrict__ w_clean,
                                                  const float* __restrict__ eps,
                                                  const unsigned int* __restrict__ scal, int sbase,
                                                  _Float16* __restrict__ We) {
    int idx = blockIdx.x*blockDim.x + threadIdx.x;   /* one thread per (o,i) */
    if (idx >= N*KQ) return;
    int o = idx / KQ, i = idx % KQ;
    float mn = dec_f(scal[sbase]), mx = dec_f(scal[sbase+1]);
    float s = (mx - mn) * (1.0f/255.0f);
    float w = w_clean[idx];
    float aw = fabsf(w) * 0.1f;
    union { _Float16 h[8]; uint4 u; } pk;
    float p = s;
    #pragma unroll
    for (int b = 0; b < 8; b++) {
        float e = eps[(size_t)b*N*KQ + idx];
        pk.h[b] = (_Float16)((w + e*aw) * p);
        p *= 2.0f;
    }
    *(uint4*)&We[((size_t)o*KQ + i)*8] = pk.u;
}

__global__ void k_bias1(const float* __restrict__ cond1, const float* __restrict__ eps1,
                        const unsigned int* __restrict__ scal, float* __restrict__ bias1) {
    int o = blockIdx.x*blockDim.x + threadIdx.x;
    if (o >= N1) return;
    float mn = dec_f(scal[0]);
    float ssum = 0.f;
    for (int i = 0; i < K1Q; i++) {
        float w = cond1[o*K1Q + i];
        float e = eps1[7*(N1*K1Q) + o*K1Q + i];   /* w_noisy[-1] = plane b=7 */
        ssum += w + (e * fabsf(w)) * 0.1f;
    }
    bias1[o] = mn * ssum;
}

__global__ void k_bias2(const float* __restrict__ cond2, const unsigned int* __restrict__ scal,
                        float* __restrict__ bias2) {
    int o = blockIdx.x*blockDim.x + threadIdx.x;
    if (o >= N2) return;
    float mn = dec_f(scal[2]);
    const float* w2 = cond2 + N2*K2Q;   /* cond2[1] — clean second matrix */
    float ssum = 0.f;
    for (int i = 0; i < K2Q; i++) ssum += w2[o*K2Q + i];
    bias2[o] = mn * ssum;
}

/* quantize c1 -> q1 m-major [m][128] bytes; thread per output dword */
__global__ __launch_bounds__(256) void k_quant_c1(const float* __restrict__ node,
                                                  const float* __restrict__ edge,
                                                  const unsigned int* __restrict__ scal,
                                                  unsigned int* __restrict__ q1) {
    int idx = blockIdx.x*256 + threadIdx.x;   /* < M1*32 */
    int m = idx >> 5, dw = idx & 31;
    const float mn = dec_f(scal[0]), rng = dec_f(scal[1]) - mn;
    float4 x;
    if (dw < 16) x = *(const float4*)&node[(m/NBR_)*FN_ + dw*4];
    else         x = *(const float4*)&edge[(size_t)m*FE_ + (dw-16)*4];
    unsigned int b0 = (unsigned char)(int)((x.x - mn) / rng * 255.0f);
    unsigned int b1 = (unsigned char)(int)((x.y - mn) / rng * 255.0f);
    unsigned int b2 = (unsigned char)(int)((x.z - mn) / rng * 255.0f);
    unsigned int b3 = (unsigned char)(int)((x.w - mn) / rng * 255.0f);
    q1[idx] = b0 | (b1 << 8) | (b2 << 16) | (b3 << 24);
}

/* quantize h -> q2 m-major [m][512] bytes */
__global__ __launch_bounds__(256) void k_quant_h(const float* __restrict__ h,
                                                 const unsigned int* __restrict__ scal,
                                                 unsigned int* __restrict__ q2) {
    int idx = blockIdx.x*256 + threadIdx.x;   /* < M1*128 */
    const float mn = dec_f(scal[2]), rng = dec_f(scal[3]) - mn;
    float4 x = *(const float4*)&h[(size_t)idx*4];
    unsigned int b0 = (unsigned char)(int)((x.x - mn) / rng * 255.0f);
    unsigned int b1 = (unsigned char)(int)((x.y - mn) / rng * 255.0f);
    unsigned int b2 = (unsigned char)(int)((x.z - mn) / rng * 255.0f);
    unsigned int b3 = (unsigned char)(int)((x.w - mn) / rng * 255.0f);
    q2[idx] = b0 | (b1 << 8) | (b2 << 16) | (b3 << 24);
}

__device__ __forceinline__ f16x8 expand_byte(unsigned int byte) {
    /* 8 bits -> 8 packed fp16 in {0.0, 1.0}; pairs via r2 = b | b<<15 */
    unsigned int r2 = byte | (byte << 15);
    union { unsigned int u[4]; f16x8 h; } t;
    t.u[0] = ( r2       & 0x00010001u) * 0x3C00u;
    t.u[1] = ((r2 >> 2) & 0x00010001u) * 0x3C00u;
    t.u[2] = ((r2 >> 4) & 0x00010001u) * 0x3C00u;
    t.u[3] = ((r2 >> 6) & 0x00010001u) * 0x3C00u;
    return t.h;
}

/* MFMA bit-plane GEMM.
   out[m,o] = sum_{i,b} bit_b(q[m,i]) * We[o][i*8+b]  (+ bias, relu, minmax for EPI1)
   Block 128x128, 4 waves 2x2, wave 64x64 = 4x4 frags of 16x16x32 fp16, BK=64 planes.
   A: lane expands one q byte per (mf,kf) -> exactly its 8 frag k-slots (m120 layout).
   B: staged global_load_lds(16B) with XOR chunk swizzle; frag via ds_read_b128. */
template<int KQ, int N, int SPLITK, bool EPI1>
__global__ __launch_bounds__(256, 2) void k_gemm16(const unsigned char* __restrict__ q,
                                                   const _Float16* __restrict__ W,
                                                   const float* __restrict__ bias,
                                                   float* __restrict__ out,
                                                   unsigned int* __restrict__ scal) {
    constexpr int KP  = KQ * 8;        /* total bit-planes */
    constexpr int KPS = KP / SPLITK;   /* planes per z-split */
    __shared__ _Float16 Bs[128*64];    /* 16 KB: [n][chunk^ (n&7)] of 8 fp16 */
    __shared__ unsigned int Qs[256];   /* 1 KB:  [m_local][2 dwords] = 8 q bytes */

    const int tid  = threadIdx.x;
    const int lane = tid & 63;
    const int w    = tid >> 6;
    const int wm   = (w & 1) * 64;
    const int wn   = (w >> 1) * 64;
    const int l15  = lane & 15;
    const int lq   = lane >> 4;        /* 0..3 */
    const int sh8  = lq * 8;
    const int m0   = blockIdx.x * 128;
    const int o0   = blockIdx.y * 128;
    const int kbase = blockIdx.z * KPS;

    f32x4 acc[4][4] = {};

    /* A-staging source: thread t -> row t>>1, dword t&1 */
    const size_t qrow = (size_t)(m0 + (tid >> 1)) * KQ + (tid & 1) * 4;
    /* B-staging: slot s = iss*256+tid -> n = s>>3, stored chunk s&7, src chunk ^(n&7) */

    #pragma unroll 1
    for (int it = 0; it < KPS/64; ++it) {
        const int kp0 = kbase + it*64;
        const int i0  = kp0 >> 3;
        __syncthreads();
        {
            unsigned int qa = *(const unsigned int*)(q + qrow + i0);
            #pragma unroll
            for (int iss = 0; iss < 4; ++iss) {
                int s   = iss*256 + tid;
                int n   = s >> 3;
                int csrc = (s & 7) ^ (n & 7);
                const _Float16* gp = W + (size_t)(o0 + n)*KP + kp0 + csrc*8;
                _Float16* lp = &Bs[(size_t)(iss*256 + (tid & ~63)) * 8];
                __builtin_amdgcn_global_load_lds((gconst_void*)gp, (lds_void*)lp, 16, 0, 0);
            }
            Qs[tid] = qa;
        }
        __builtin_amdgcn_s_waitcnt(0);
        __syncthreads();

        f16x8 bf[4][2];
        #pragma unroll
        for (int nf = 0; nf < 4; ++nf) {
            const int nl = wn + nf*16 + l15;
            #pragma unroll
            for (int kf = 0; kf < 2; ++kf) {
                const int ch = kf*4 + lq;
                bf[nf][kf] = *(const f16x8*)&Bs[nl*64 + ((ch ^ (nl & 7)) << 3)];
            }
        }
        #pragma unroll
        for (int mf = 0; mf < 4; ++mf) {
            uint2 qd = *(const uint2*)&Qs[(wm + mf*16 + l15) * 2];
            f16x8 a0 = expand_byte((qd.x >> sh8) & 0xFFu);
            f16x8 a1 = expand_byte((qd.y >> sh8) & 0xFFu);
            #pragma unroll
            for (int nf = 0; nf < 4; ++nf) {
                acc[mf][nf] = __builtin_amdgcn_mfma_f32_16x16x32_f16(a0, bf[nf][0], acc[mf][nf], 0, 0, 0);
                acc[mf][nf] = __builtin_amdgcn_mfma_f32_16x16x32_f16(a1, bf[nf][1], acc[mf][nf], 0, 0, 0);
            }
        }
    }

    /* epilogue: C/D layout col = lane&15, row = (lane>>4)*4 + r  (m89) */
    if (EPI1) {
        float bv[4];
        #pragma unroll
        for (int nf = 0; nf < 4; ++nf) bv[nf] = bias[o0 + wn + nf*16 + l15];
        float tmn = 3.0e38f, tmx = -3.0e38f;
        #pragma unroll
        for (int mf = 0; mf < 4; ++mf) {
            const int mr = m0 + wm + mf*16 + lq*4;
            #pragma unroll
            for (int nf = 0; nf < 4; ++nf) {
                const int oc = o0 + wn + nf*16 + l15;
                #pragma unroll
                for (int r = 0; r < 4; ++r) {
                    float v = acc[mf][nf][r] + bv[nf];
                    v = fmaxf(v, 0.0f);
                    tmn = fminf(tmn, v); tmx = fmaxf(tmx, v);
                    out[(size_t)(mr + r)*N + oc] = v;
                }
            }
        }
        __syncthreads();
        float* red = (float*)Bs;
        red[tid] = tmn; red[256 + tid] = tmx;
        __syncthreads();
        for (int s = 128; s > 0; s >>= 1) {
            if (tid < s) {
                red[tid]       = fminf(red[tid],       red[tid + s]);
                red[256 + tid] = fmaxf(red[256 + tid], red[256 + tid + s]);
            }
            __syncthreads();
        }
        if (tid == 0) { atomicMin(&scal[2], enc_f(red[0])); atomicMax(&scal[3], enc_f(red[256])); }
    } else {
        float* op = out + (size_t)blockIdx.z * ((size_t)M1 * N);
        #pragma unroll
        for (int mf = 0; mf < 4; ++mf) {
            const int mr = m0 + wm + mf*16 + lq*4;
            #pragma unroll
            for (int nf = 0; nf < 4; ++nf) {
                const int oc = o0 + wn + nf*16 + l15;
                #pragma unroll
                for (int r = 0; r < 4; ++r)
                    op[(size_t)(mr + r)*N + oc] = acc[mf][nf][r];
            }
        }
    }
}

/* gate/extract from split-K partials -> sigmoid*tanh*mask, sum over 12 neighbors */
__global__ void k_nbr(const float* __restrict__ zp, const float* __restrict__ bias2,
                      const float* __restrict__ mask, float* __restrict__ ns) {
    const size_t SP = (size_t)M1 * N2;
    int r = blockIdx.x;     /* 0..1535 */
    int f = threadIdx.x;    /* 0..63   */
    float bg = bias2[f], be = bias2[64 + f];
    float s = 0.f;
    #pragma unroll
    for (int n = 0; n < NBR_; n++) {
        int m = r*NBR_ + n;
        size_t base = (size_t)m * N2;
        float g = bg, e = be;
        #pragma unroll
        for (int z = 0; z < SPLIT2; z++) {
            g += zp[z*SP + base + f];
            e += zp[z*SP + base + 64 + f];
        }
        float sig = 1.0f / (1.0f + expf(-g));
        s += sig * tanhf(e) * mask[m];
    }
    ns[r*64 + f] = s;
}

/* BatchNorm (batch stats over 1536 rows) + residual + relu; one block per feature */
__global__ __launch_bounds__(256) void k_bn(const float* __restrict__ ns,
                                            const float* __restrict__ node,
                                            const float* __restrict__ gamma,
                                            const float* __restrict__ beta,
                                            float* __restrict__ out) {
    int f = blockIdx.x;
    int tid = threadIdx.x;
    float x[6];
    float s = 0.f, ss = 0.f;
    #pragma unroll
    for (int k = 0; k < 6; k++) {
        int r = tid + k*256;
        x[k] = ns[r*64 + f];
        s += x[k]; ss += x[k]*x[k];
    }
    __shared__ float rs[256], rss[256];
    rs[tid] = s; rss[tid] = ss; __syncthreads();
    for (int st = 128; st > 0; st >>= 1) {
        if (tid < st) { rs[tid] += rs[tid+st]; rss[tid] += rss[tid+st]; }
        __syncthreads();
    }
    float mean = rs[0] / 1536.0f;
    float var  = rss[0] / 1536.0f - mean*mean;
    float denom = sqrtf(var + 1e-5f);
    float g = gamma[f], bt = beta[f];
    #pragma unroll
    for (int k = 0; k < 6; k++) {
        int r = tid + k*256;
        float v = node[r*64 + f] + ((x[k] - mean) / denom * g + bt);
        out[r*64 + f] = fmaxf(v, 0.f);
    }
}

extern "C" void kernel_launch(void* const* d_in, const int* in_sizes, int n_in,
                              void* d_out, int out_size, void* d_ws, size_t ws_size,
                              hipStream_t stream) {
    const float* node  = (const float*)d_in[0];
    const float* edge  = (const float*)d_in[1];
    const float* mask  = (const float*)d_in[2];
    const float* cond1 = (const float*)d_in[3];
    const float* cond2 = (const float*)d_in[4];
    const float* eps1  = (const float*)d_in[5];
    const float* eps2  = (const float*)d_in[6];
    const float* gamma = (const float*)d_in[7];
    const float* beta  = (const float*)d_in[8];
    float* out = (float*)d_out;
    char* ws = (char*)d_ws;

    unsigned int*  scal = (unsigned int*)(ws + OFF_SCAL);
    unsigned char* q1   = (unsigned char*)(ws + OFF_Q1);
    _Float16* W1e = (_Float16*)(ws + OFF_W1E);
    float*    b1  = (float*)(ws + OFF_B1);
    float*    b2  = (float*)(ws + OFF_B2);
    _Float16* W2e = (_Float16*)(ws + OFF_W2E);
    unsigned char* q2 = (unsigned char*)(ws + OFF_Q2);
    float* h  = (float*)(ws + OFF_H);
    float* zp = (float*)(ws + OFF_ZP);
    float* ns = (float*)(ws + OFF_NS);

    k_init<<<1, 64, 0, stream>>>(scal);
    k_minmax_c1<<<512, 256, 0, stream>>>(node, edge, scal);
    k_prep_w16<K1Q, N1><<<(N1*K1Q + 255)/256, 256, 0, stream>>>(cond1, eps1, scal, 0, W1e);
    k_bias1<<<(N1 + 63)/64, 64, 0, stream>>>(cond1, eps1, scal, b1);
    k_quant_c1<<<(M1*32)/256, 256, 0, stream>>>(node, edge, scal, (unsigned int*)q1);
    k_gemm16<K1Q, N1, 1, true><<<dim3(M1/128, N1/128, 1), 256, 0, stream>>>(q1, W1e, b1, h, scal);
    k_prep_w16<K2Q, N2><<<(N2*K2Q + 255)/256, 256, 0, stream>>>(cond2, eps2, scal, 2, W2e);
    k_bias2<<<(N2 + 63)/64, 64, 0, stream>>>(cond2, scal, b2);
    k_quant_h<<<(M1*128)/256, 256, 0, stream>>>(h, scal, (unsigned int*)q2);
    k_gemm16<K2Q, N2, SPLIT2, false><<<dim3(M1/128, N2/128, SPLIT2), 256, 0, stream>>>(q2, W2e, (const float*)nullptr, zp, scal);
    k_nbr<<<R_, 64, 0, stream>>>(zp, b2, mask, ns);
    k_bn<<<64, 256, 0, stream>>>(ns, node, gamma, beta, out);
}

// Round 3
// 198.785 us; speedup vs baseline: 3.7727x; 1.0669x over previous
//
#include <hip/hip_runtime.h>
#include <stdint.h>

#define B_    16
#define AT_   96
#define NBR_  12
#define FN_   64
#define FE_   64
#define M1    (B_*AT_*NBR_)   /* 18432 */
#define R_    (B_*AT_)        /* 1536  */
#define K1Q   128             /* layer-1 input features (bytes per row) */
#define N1    512             /* H1 */
#define K2Q   512
#define N2    128
#define SPLIT2 4

typedef _Float16 f16x8 __attribute__((ext_vector_type(8)));
typedef float    f32x4 __attribute__((ext_vector_type(4)));
typedef __attribute__((address_space(1))) const void gconst_void;
typedef __attribute__((address_space(3))) void lds_void;

/* ---- workspace layout (bytes) ---- */
#define OFF_SCAL  0u
#define OFF_B1R   256u                                  /* fp32 512  */
#define OFF_B2R   (OFF_B1R + 2048u)                     /* fp32 128  */
#define OFF_Q1    4096u                                 /* u8 M1*128 = 2.25 MB */
#define OFF_W1E   (OFF_Q1  + (size_t)M1*K1Q)            /* fp16 512*1024 = 1 MB */
#define OFF_W2E   (OFF_W1E + (size_t)N1*K1Q*8*2)        /* fp16 128*4096 = 1 MB */
#define OFF_Q2    (OFF_W2E + (size_t)N2*K2Q*8*2)        /* u8 M1*512 = 9 MB */
#define OFF_H     (OFF_Q2  + (size_t)M1*K2Q)            /* fp32 M1*512 = 37.75 MB */
#define OFF_ZP    OFF_H                                  /* fp16 4*M1*128 = 18.9 MB; h dead after quant_h */
#define OFF_NS    (OFF_H   + (size_t)M1*N1*4)           /* fp32 1536*64 */

__device__ __forceinline__ unsigned int enc_f(float f) {
    unsigned int u = __float_as_uint(f);
    return (u & 0x80000000u) ? ~u : (u | 0x80000000u);
}
__device__ __forceinline__ float dec_f(unsigned int u) {
    return __uint_as_float((u & 0x80000000u) ? (u & 0x7FFFFFFFu) : ~u);
}

/* init scal + zero bias accumulators (ws is poisoned 0xAA every launch) */
__global__ void k_init(unsigned int* scal, float* b1raw, float* b2raw) {
    int t = threadIdx.x;
    if (t == 0) { scal[0] = 0xFFFFFFFFu; scal[1] = 0u; scal[2] = 0xFFFFFFFFu; scal[3] = 0u; }
    if (t < N1) b1raw[t] = 0.f;
    if (t < N2) b2raw[t] = 0.f;
}

__global__ __launch_bounds__(256) void k_minmax_c1(const float* __restrict__ node,
                                                   const float* __restrict__ edge,
                                                   unsigned int* __restrict__ scal) {
    const int nn = B_*AT_*FN_;
    const int ntot = nn + M1*FE_;
    float mn = 3.0e38f, mx = -3.0e38f;
    for (int idx = blockIdx.x*blockDim.x + threadIdx.x; idx < ntot; idx += gridDim.x*blockDim.x) {
        float x = (idx < nn) ? node[idx] : edge[idx - nn];
        mn = fminf(mn, x); mx = fmaxf(mx, x);
    }
    __shared__ float smn[256], smx[256];
    smn[threadIdx.x] = mn; smx[threadIdx.x] = mx; __syncthreads();
    for (int s = 128; s > 0; s >>= 1) {
        if (threadIdx.x < s) {
            smn[threadIdx.x] = fminf(smn[threadIdx.x], smn[threadIdx.x+s]);
            smx[threadIdx.x] = fmaxf(smx[threadIdx.x], smx[threadIdx.x+s]);
        }
        __syncthreads();
    }
    if (threadIdx.x == 0) { atomicMin(&scal[0], enc_f(smn[0])); atomicMax(&scal[1], enc_f(smx[0])); }
}

/* expanded fp16 weights, o-major: We[o][k=i*8+b] = fp16( (w+0.1|w|eps_b) * 2^b * s )
   + fused bias-sum accumulation (wave-reduce, 1 atomic per wave):
     USE_SECOND=false: bias contrib = plane-7 noisy value (layer 1)
     USE_SECOND=true : bias contrib = w_clean[1][o][i]      (layer 2) */
template<int KQ, int N, int SBASE, bool USE_SECOND>
__global__ __launch_bounds__(256) void k_prep_w16(const float* __restrict__ w_clean,
                                                  const float* __restrict__ eps,
                                                  const unsigned int* __restrict__ scal,
                                                  float* __restrict__ braw,
                                                  _Float16* __restrict__ We) {
    int idx = blockIdx.x*blockDim.x + threadIdx.x;   /* one thread per (o,i) */
    if (idx >= N*KQ) return;
    int o = idx / KQ;
    int i = idx % KQ;
    float mn = dec_f(scal[SBASE]), mx = dec_f(scal[SBASE+1]);
    float s = (mx - mn) * (1.0f/255.0f);
    float w = w_clean[idx];
    float aw = fabsf(w) * 0.1f;
    union { _Float16 h[8]; uint4 u; } pk;
    float p = s;
    float v7 = 0.f;
    #pragma unroll
    for (int b = 0; b < 8; b++) {
        float e = eps[(size_t)b*N*KQ + idx];
        float v = w + e*aw;
        if (b == 7) v7 = v;
        pk.h[b] = (_Float16)(v * p);
        p *= 2.0f;
    }
    *(uint4*)&We[((size_t)o*KQ + i)*8] = pk.u;
    /* bias-sum: wave spans 64 consecutive i of one o (KQ multiple of 64) */
    float bv = USE_SECOND ? w_clean[(size_t)N*KQ + idx] : v7;
    #pragma unroll
    for (int off = 32; off > 0; off >>= 1) bv += __shfl_down(bv, off);
    if ((threadIdx.x & 63) == 0) atomicAdd(&braw[o], bv);
}

/* quantize c1 -> q1 m-major [m][128] bytes; thread per output dword */
__global__ __launch_bounds__(256) void k_quant_c1(const float* __restrict__ node,
                                                  const float* __restrict__ edge,
                                                  const unsigned int* __restrict__ scal,
                                                  unsigned int* __restrict__ q1) {
    int idx = blockIdx.x*256 + threadIdx.x;   /* < M1*32 */
    int m = idx >> 5, dw = idx & 31;
    const float mn = dec_f(scal[0]), rng = dec_f(scal[1]) - mn;
    float4 x;
    if (dw < 16) x = *(const float4*)&node[(m/NBR_)*FN_ + dw*4];
    else         x = *(const float4*)&edge[(size_t)m*FE_ + (dw-16)*4];
    unsigned int b0 = (unsigned char)(int)((x.x - mn) / rng * 255.0f);
    unsigned int b1 = (unsigned char)(int)((x.y - mn) / rng * 255.0f);
    unsigned int b2 = (unsigned char)(int)((x.z - mn) / rng * 255.0f);
    unsigned int b3 = (unsigned char)(int)((x.w - mn) / rng * 255.0f);
    q1[idx] = b0 | (b1 << 8) | (b2 << 16) | (b3 << 24);
}

/* quantize h -> q2 m-major [m][512] bytes */
__global__ __launch_bounds__(256) void k_quant_h(const float* __restrict__ h,
                                                 const unsigned int* __restrict__ scal,
                                                 unsigned int* __restrict__ q2) {
    int idx = blockIdx.x*256 + threadIdx.x;   /* < M1*128 */
    const float mn = dec_f(scal[2]), rng = dec_f(scal[3]) - mn;
    float4 x = *(const float4*)&h[(size_t)idx*4];
    unsigned int b0 = (unsigned char)(int)((x.x - mn) / rng * 255.0f);
    unsigned int b1 = (unsigned char)(int)((x.y - mn) / rng * 255.0f);
    unsigned int b2 = (unsigned char)(int)((x.z - mn) / rng * 255.0f);
    unsigned int b3 = (unsigned char)(int)((x.w - mn) / rng * 255.0f);
    q2[idx] = b0 | (b1 << 8) | (b2 << 16) | (b3 << 24);
}

__device__ __forceinline__ f16x8 expand_byte(unsigned int byte) {
    /* 8 bits -> 8 packed fp16 in {0.0, 1.0}; pairs via r2 = b | b<<15 */
    unsigned int r2 = byte | (byte << 15);
    union { unsigned int u[4]; f16x8 h; } t;
    t.u[0] = ( r2       & 0x00010001u) * 0x3C00u;
    t.u[1] = ((r2 >> 2) & 0x00010001u) * 0x3C00u;
    t.u[2] = ((r2 >> 4) & 0x00010001u) * 0x3C00u;
    t.u[3] = ((r2 >> 6) & 0x00010001u) * 0x3C00u;
    return t.h;
}

/* MFMA bit-plane GEMM, K-group-wave structure.
   Block tile 128m x 64n, 4 waves = 2 (m) x 2 (K-half); each wave 64x64 via
   4x4 frags of 16x16x32 f16, BK=64 planes per group per iter (128/block-iter).
   K-halves LDS-reduced at the end. Grid 1152 blocks -> ~4.5 waves/SIMD.
   __launch_bounds__(256,4): VGPR<=128 so 2 blocks/CU (4 waves/SIMD) resident. */
template<int KQ, int N, int SPLITK, bool EPI1>
__global__ __launch_bounds__(256, 4) void kg(const unsigned char* __restrict__ q,
                                             const _Float16* __restrict__ W,
                                             const float* __restrict__ braw,
                                             void* __restrict__ outv,
                                             unsigned int* __restrict__ scal) {
    constexpr int KP  = KQ * 8;        /* total bit-planes */
    constexpr int KPS = KP / SPLITK;   /* planes per z-split (1024 both layers) */
    __shared__ _Float16 Bs[8192];      /* 16 KB: [kg][n][chunk^(n&7)] of 8 fp16 */
    __shared__ uint2    Qs[256];       /* 2 KB:  [kg][m_local] 8 q bytes */

    const int tid  = threadIdx.x;
    const int lane = tid & 63;
    const int w    = tid >> 6;
    const int wm   = (w & 1) * 64;
    const int kg   = w >> 1;           /* K-group of this wave */
    const int l15  = lane & 15;
    const int lq   = lane >> 4;
    const int sh8  = lq * 8;
    const int m0   = blockIdx.x * 128;
    const int o0   = blockIdx.y * 64;
    const int kbase = blockIdx.z * KPS;

    f32x4 acc[4][4] = {};

    /* A staging: thread covers (group tid>>7, row tid&127), 8 B per iter */
    const int akg = tid >> 7, agt = tid & 127;
    const unsigned char* aq = q + (size_t)(m0 + agt)*KQ + (kbase >> 3) + akg*64;

    #pragma unroll 1
    for (int it = 0; it < KPS/128; ++it) {
        __syncthreads();
        uint2 qa = *(const uint2*)(aq + it*8);
        #pragma unroll
        for (int iss = 0; iss < 4; ++iss) {
            int s    = iss*256 + tid;
            int skg  = s >> 9;
            int sg   = s & 511;
            int n    = sg >> 3;
            int csrc = (sg & 7) ^ (n & 7);
            const _Float16* gp = W + (size_t)(o0 + n)*KP + kbase + skg*512 + it*64 + csrc*8;
            _Float16* lp = &Bs[(size_t)(iss*256 + (tid & ~63)) * 8];
            __builtin_amdgcn_global_load_lds((gconst_void*)gp, (lds_void*)lp, 16, 0, 0);
        }
        Qs[(akg << 7) + agt] = qa;
        __builtin_amdgcn_s_waitcnt(0);
        __syncthreads();

        uint2 qd[4];
        #pragma unroll
        for (int mf = 0; mf < 4; ++mf)
            qd[mf] = Qs[kg*128 + wm + mf*16 + l15];
        #pragma unroll
        for (int kf = 0; kf < 2; ++kf) {
            f16x8 bf[4];
            #pragma unroll
            for (int nf = 0; nf < 4; ++nf) {
                const int nl = nf*16 + l15;
                const int ch = kf*4 + lq;
                bf[nf] = *(const f16x8*)&Bs[kg*4096 + nl*64 + ((ch ^ (nl & 7)) << 3)];
            }
            #pragma unroll
            for (int mf = 0; mf < 4; ++mf) {
                unsigned int byte = ((kf ? qd[mf].y : qd[mf].x) >> sh8) & 0xFFu;
                f16x8 a = expand_byte(byte);
                #pragma unroll
                for (int nf = 0; nf < 4; ++nf)
                    acc[mf][nf] = __builtin_amdgcn_mfma_f32_16x16x32_f16(a, bf[nf], acc[mf][nf], 0, 0, 0);
            }
        }
    }

    /* K-group reduction: kg=1 waves hand their acc to kg=0 partners via LDS */
    float* red = (float*)Bs;
    #pragma unroll
    for (int nf = 0; nf < 4; ++nf) {
        __syncthreads();
        if (kg == 1) {
            #pragma unroll
            for (int mf = 0; mf < 4; ++mf)
                *(f32x4*)&red[(w & 1)*1024 + mf*256 + lane*4] = acc[mf][nf];
        }
        __syncthreads();
        if (kg == 0) {
            #pragma unroll
            for (int mf = 0; mf < 4; ++mf)
                acc[mf][nf] += *(const f32x4*)&red[(w & 1)*1024 + mf*256 + lane*4];
        }
    }

    /* epilogue: C/D layout col = lane&15, row = (lane>>4)*4 + r  (m89) */
    if (EPI1) {
        float tmn = 3.0e38f, tmx = -3.0e38f;
        if (kg == 0) {
            float* out = (float*)outv;
            const float mn1 = dec_f(scal[0]);
            float bv[4];
            #pragma unroll
            for (int nf = 0; nf < 4; ++nf) bv[nf] = mn1 * braw[o0 + nf*16 + l15];
            #pragma unroll
            for (int mf = 0; mf < 4; ++mf) {
                const int mr = m0 + wm + mf*16 + lq*4;
                #pragma unroll
                for (int nf = 0; nf < 4; ++nf) {
                    const int oc = o0 + nf*16 + l15;
                    #pragma unroll
                    for (int r = 0; r < 4; ++r) {
                        float v = acc[mf][nf][r] + bv[nf];
                        v = fmaxf(v, 0.0f);
                        tmn = fminf(tmn, v); tmx = fmaxf(tmx, v);
                        out[(size_t)(mr + r)*N + oc] = v;
                    }
                }
            }
        }
        __syncthreads();
        red[tid] = tmn; red[256 + tid] = tmx;
        __syncthreads();
        for (int s = 128; s > 0; s >>= 1) {
            if (tid < s) {
                red[tid]       = fminf(red[tid],       red[tid + s]);
                red[256 + tid] = fmaxf(red[256 + tid], red[256 + tid + s]);
            }
            __syncthreads();
        }
        if (tid == 0) { atomicMin(&scal[2], enc_f(red[0])); atomicMax(&scal[3], enc_f(red[256])); }
    } else {
        if (kg == 0) {
            _Float16* op = (_Float16*)outv + (size_t)blockIdx.z * ((size_t)M1 * N);
            #pragma unroll
            for (int mf = 0; mf < 4; ++mf) {
                const int mr = m0 + wm + mf*16 + lq*4;
                #pragma unroll
                for (int nf = 0; nf < 4; ++nf) {
                    const int oc = o0 + nf*16 + l15;
                    #pragma unroll
                    for (int r = 0; r < 4; ++r)
                        op[(size_t)(mr + r)*N + oc] = (_Float16)acc[mf][nf][r];
                }
            }
        }
    }
}

/* gate/extract from fp16 split-K partials -> sigmoid*tanh*mask, sum over neighbors */
__global__ __launch_bounds__(256) void k_nbr(const _Float16* __restrict__ zp,
                                             const float* __restrict__ b2raw,
                                             const unsigned int* __restrict__ scal,
                                             const float* __restrict__ mask,
                                             float* __restrict__ ns) {
    const size_t SP = (size_t)M1 * N2;
    int tid = threadIdx.x;
    int r = blockIdx.x*4 + (tid >> 6);   /* 0..1535 */
    int f = tid & 63;
    const float mn2 = dec_f(scal[2]);
    float bg = mn2 * b2raw[f], be = mn2 * b2raw[64 + f];
    float s = 0.f;
    #pragma unroll
    for (int n = 0; n < NBR_; n++) {
        int m = r*NBR_ + n;
        size_t base = (size_t)m * N2;
        float g = bg, e = be;
        #pragma unroll
        for (int z = 0; z < SPLIT2; z++) {
            g += (float)zp[z*SP + base + f];
            e += (float)zp[z*SP + base + 64 + f];
        }
        float sig = 1.0f / (1.0f + expf(-g));
        s += sig * tanhf(e) * mask[m];
    }
    ns[r*64 + f] = s;
}

/* BatchNorm (batch stats over 1536 rows) + residual + relu; one block per feature */
__global__ __launch_bounds__(256) void k_bn(const float* __restrict__ ns,
                                            const float* __restrict__ node,
                                            const float* __restrict__ gamma,
                                            const float* __restrict__ beta,
                                            float* __restrict__ out) {
    int f = blockIdx.x;
    int tid = threadIdx.x;
    float x[6];
    float s = 0.f, ss = 0.f;
    #pragma unroll
    for (int k = 0; k < 6; k++) {
        int r = tid + k*256;
        x[k] = ns[r*64 + f];
        s += x[k]; ss += x[k]*x[k];
    }
    __shared__ float rs[256], rss[256];
    rs[tid] = s; rss[tid] = ss; __syncthreads();
    for (int st = 128; st > 0; st >>= 1) {
        if (tid < st) { rs[tid] += rs[tid+st]; rss[tid] += rss[tid+st]; }
        __syncthreads();
    }
    float mean = rs[0] / 1536.0f;
    float var  = rss[0] / 1536.0f - mean*mean;
    float denom = sqrtf(var + 1e-5f);
    float g = gamma[f], bt = beta[f];
    #pragma unroll
    for (int k = 0; k < 6; k++) {
        int r = tid + k*256;
        float v = node[r*64 + f] + ((x[k] - mean) / denom * g + bt);
        out[r*64 + f] = fmaxf(v, 0.f);
    }
}

extern "C" void kernel_launch(void* const* d_in, const int* in_sizes, int n_in,
                              void* d_out, int out_size, void* d_ws, size_t ws_size,
                              hipStream_t stream) {
    const float* node  = (const float*)d_in[0];
    const float* edge  = (const float*)d_in[1];
    const float* mask  = (const float*)d_in[2];
    const float* cond1 = (const float*)d_in[3];
    const float* cond2 = (const float*)d_in[4];
    const float* eps1  = (const float*)d_in[5];
    const float* eps2  = (const float*)d_in[6];
    const float* gamma = (const float*)d_in[7];
    const float* beta  = (const float*)d_in[8];
    float* out = (float*)d_out;
    char* ws = (char*)d_ws;

    unsigned int*  scal = (unsigned int*)(ws + OFF_SCAL);
    float* b1raw = (float*)(ws + OFF_B1R);
    float* b2raw = (float*)(ws + OFF_B2R);
    unsigned char* q1 = (unsigned char*)(ws + OFF_Q1);
    _Float16* W1e = (_Float16*)(ws + OFF_W1E);
    _Float16* W2e = (_Float16*)(ws + OFF_W2E);
    unsigned char* q2 = (unsigned char*)(ws + OFF_Q2);
    float*    h  = (float*)(ws + OFF_H);
    _Float16* zp = (_Float16*)(ws + OFF_ZP);
    float*    ns = (float*)(ws + OFF_NS);

    k_init<<<1, 1024, 0, stream>>>(scal, b1raw, b2raw);
    k_minmax_c1<<<512, 256, 0, stream>>>(node, edge, scal);
    k_prep_w16<K1Q, N1, 0, false><<<(N1*K1Q + 255)/256, 256, 0, stream>>>(cond1, eps1, scal, b1raw, W1e);
    k_quant_c1<<<(M1*32)/256, 256, 0, stream>>>(node, edge, scal, (unsigned int*)q1);
    kg<K1Q, N1, 1, true><<<dim3(M1/128, N1/64, 1), 256, 0, stream>>>(q1, W1e, b1raw, h, scal);
    k_prep_w16<K2Q, N2, 2, true><<<(N2*K2Q + 255)/256, 256, 0, stream>>>(cond2, eps2, scal, b2raw, W2e);
    k_quant_h<<<(M1*128)/256, 256, 0, stream>>>(h, scal, (unsigned int*)q2);
    kg<K2Q, N2, SPLIT2, false><<<dim3(M1/128, N2/64, SPLIT2), 256, 0, stream>>>(q2, W2e, b2raw, zp, scal);
    k_nbr<<<R_/4, 256, 0, stream>>>(zp, b2raw, scal, mask, ns);
    k_bn<<<64, 256, 0, stream>>>(ns, node, gamma, beta, out);
}